// Round 1
// baseline (265.109 us; speedup 1.0000x reference)
//
#include <hip/hip_runtime.h>

// Izhikevich neuron scan. x: [B=16, C=64, N=1024, T=32] f32, T contiguous.
// 1M independent neurons, 32-step sequential recurrence each.
// Memory-bound: 256 MB total traffic -> ~41 us roofline at 6.3 TB/s.
//
// Numerics: must match the numpy float32 reference bit-exactly (recurrence
// amplifies ulp errors up to ~8x/step near spiking; a flipped spike = 1.0
// error vs 2e-2 threshold). Hence: fp contract OFF, explicit left-assoc
// parens mirroring Python eval order, literal spike-blend arithmetic.

#define T_STEPS 32

__global__ __launch_bounds__(256) void izhikevich_kernel(
    const float* __restrict__ x,
    const float* __restrict__ pa,
    const float* __restrict__ pb,
    const float* __restrict__ pc,
    const float* __restrict__ pd,
    float* __restrict__ out,
    int n_neurons)
{
#pragma clang fp contract(off)
    const int n = blockIdx.x * blockDim.x + threadIdx.x;
    if (n >= n_neurons) return;

    const float a = pa[0];
    const float b = pb[0];
    const float c = pc[0];
    const float d = pd[0];

    const float4* __restrict__ xp =
        reinterpret_cast<const float4*>(x + (size_t)n * T_STEPS);
    float4* __restrict__ op =
        reinterpret_cast<float4*>(out + (size_t)n * T_STEPS);

    // Load all 32 x values up-front: 8 outstanding float4 loads for latency
    // hiding. Lanes stride 128 B, but all fetched lines are fully consumed
    // across the 8 instructions -> sequential HBM stream, no over-fetch.
    float4 xs[8];
#pragma unroll
    for (int k = 0; k < 8; ++k) xs[k] = xp[k];
    const float* xf = reinterpret_cast<const float*>(xs);

    float v = 0.0f;
    float u = 0.0f;

#pragma unroll
    for (int k = 0; k < 8; ++k) {
        float4 sp;
        float* sf = reinterpret_cast<float*>(&sp);
#pragma unroll
        for (int j = 0; j < 4; ++j) {
            const float xt = xf[k * 4 + j];
            // dv = 0.04*v*v + 5.0*v + 140.0 - u + x_t   (left-assoc)
            const float t1 = (0.04f * v) * v;
            const float t2 = 5.0f * v;
            const float dv = (((t1 + t2) + 140.0f) - u) + xt;
            // v = v + DT*dv, DT = 1.0 (multiply by 1.0 is exact)
            v = v + dv;
            // du = a * (b*v - u);  u = u + DT*du
            const float du = a * ((b * v) - u);
            u = u + du;
            // spike = (v >= 30)
            const float spike = (v >= 30.0f) ? 1.0f : 0.0f;
            // v = v*(1-spike) + c*spike  (exact for spike in {0,1})
            const float oms = 1.0f - spike;
            v = (v * oms) + (c * spike);
            // u = u + d*spike
            u = u + (d * spike);
            sf[j] = spike;
        }
        op[k] = sp;
    }
}

extern "C" void kernel_launch(void* const* d_in, const int* in_sizes, int n_in,
                              void* d_out, int out_size, void* d_ws, size_t ws_size,
                              hipStream_t stream) {
    const float* x  = (const float*)d_in[0];
    const float* pa = (const float*)d_in[1];
    const float* pb = (const float*)d_in[2];
    const float* pc = (const float*)d_in[3];
    const float* pd = (const float*)d_in[4];
    float* out = (float*)d_out;

    const int n_neurons = in_sizes[0] / T_STEPS;  // 1,048,576
    const int block = 256;
    const int grid = (n_neurons + block - 1) / block;

    izhikevich_kernel<<<grid, block, 0, stream>>>(x, pa, pb, pc, pd, out,
                                                  n_neurons);
}

// Round 2
// 239.462 us; speedup vs baseline: 1.1071x; 1.1071x over previous
//
#include <hip/hip_runtime.h>

// Izhikevich neuron scan. x: [B=16, C=64, N=1024, T=32] f32, T contiguous.
// 1M independent neurons, 32-step sequential recurrence each.
//
// R1 post-mortem: per-lane 128B-strided float4 access fragmented every VMEM
// instruction into 64 cache-line requests (4x TA/L2 request count) and
// produced partial-line stores (WRITE_SIZE 157MB vs 128MB ideal). Waves sat
// in vmcnt stalls: 2.35 TB/s, VALUBusy 16%.
//
// R2: LDS transpose. Coalesced float4 global loads -> LDS (row stride 33
// floats: phase-2/3 accesses are exactly 2 lanes/bank = free, m136), per-
// thread recurrence in registers, spikes written back in-place to the
// thread's own row (exclusive ownership -> no barrier), one barrier, then
// coalesced float4 stores. All global transactions are full lines.
//
// Numerics: bit-exact f32 replication of the numpy reference (contract off,
// left-assoc order). LDS round-trip preserves bits.

#define T_STEPS 32
#define TPB 256
#define ROW 33  // padded LDS row stride (floats): bank (t*33+j)%32 = (t+j)%32

__global__ __launch_bounds__(TPB) void izhikevich_kernel(
    const float* __restrict__ x,
    const float* __restrict__ pa,
    const float* __restrict__ pb,
    const float* __restrict__ pc,
    const float* __restrict__ pd,
    float* __restrict__ out)
{
#pragma clang fp contract(off)
    __shared__ float lds[TPB * ROW];

    const int t = threadIdx.x;
    const size_t blockBase = (size_t)blockIdx.x * (TPB * T_STEPS);

    const float a = pa[0];
    const float b = pb[0];
    const float c = pc[0];
    const float d = pd[0];

    // ---- Phase 1: coalesced global -> LDS (transposing scatter) ----------
    // Instruction k, lane t loads elements (k*1024 + 4t .. +3): fully
    // coalesced 1 KiB/wave-instruction. Element e -> neuron e/32, time e%32.
    const float4* __restrict__ xin =
        reinterpret_cast<const float4*>(x + blockBase);
#pragma unroll
    for (int k = 0; k < 8; ++k) {
        const float4 ch = xin[k * TPB + t];
        const int ng = k * 32 + (t >> 3);       // neuron within block
        const int tg = (t & 7) * 4;             // time offset
        float* row = &lds[ng * ROW + tg];       // bank: 2 lanes/bank -> free
        row[0] = ch.x; row[1] = ch.y; row[2] = ch.z; row[3] = ch.w;
    }
    __syncthreads();

    // ---- Phase 2: per-thread row read (imm-offset ds_read, 2-way free) ---
    float xs[T_STEPS];
#pragma unroll
    for (int j = 0; j < T_STEPS; ++j) xs[j] = lds[t * ROW + j];

    // ---- Phase 3: recurrence, spikes written back in-place (own row) -----
    float v = 0.0f;
    float u = 0.0f;
#pragma unroll
    for (int j = 0; j < T_STEPS; ++j) {
        const float xt = xs[j];
        // dv = 0.04*v*v + 5.0*v + 140.0 - u + x_t   (left-assoc, no fma)
        const float t1 = (0.04f * v) * v;
        const float t2 = 5.0f * v;
        const float dv = (((t1 + t2) + 140.0f) - u) + xt;
        v = v + dv;                              // DT = 1.0 exact
        const float du = a * ((b * v) - u);
        u = u + du;
        const float spike = (v >= 30.0f) ? 1.0f : 0.0f;
        const float oms = 1.0f - spike;
        v = (v * oms) + (c * spike);             // exact for spike in {0,1}
        u = u + (d * spike);
        lds[t * ROW + j] = spike;                // own row: no barrier needed
    }
    __syncthreads();

    // ---- Phase 4: LDS -> coalesced global float4 stores ------------------
    float4* __restrict__ op = reinterpret_cast<float4*>(out + blockBase);
#pragma unroll
    for (int k = 0; k < 8; ++k) {
        const int ng = k * 32 + (t >> 3);
        const int tg = (t & 7) * 4;
        const float* row = &lds[ng * ROW + tg];
        float4 o;
        o.x = row[0]; o.y = row[1]; o.z = row[2]; o.w = row[3];
        op[k * TPB + t] = o;                     // full-line coalesced store
    }
}

extern "C" void kernel_launch(void* const* d_in, const int* in_sizes, int n_in,
                              void* d_out, int out_size, void* d_ws, size_t ws_size,
                              hipStream_t stream) {
    const float* x  = (const float*)d_in[0];
    const float* pa = (const float*)d_in[1];
    const float* pb = (const float*)d_in[2];
    const float* pc = (const float*)d_in[3];
    const float* pd = (const float*)d_in[4];
    float* out = (float*)d_out;

    const int n_neurons = in_sizes[0] / T_STEPS;   // 1,048,576
    const int grid = n_neurons / TPB;              // 4096 (exact)

    izhikevich_kernel<<<grid, TPB, 0, stream>>>(x, pa, pb, pc, pd, out);
}

// Round 3
// 238.865 us; speedup vs baseline: 1.1099x; 1.0025x over previous
//
#include <hip/hip_runtime.h>

// Izhikevich neuron scan. x: [B=16, C=64, N=1024, T=32] f32, T contiguous.
// 1M independent neurons, 32-step sequential recurrence each.
//
// R2 post-mortem: 4-wave blocks + __syncthreads created a phase-locked
// convoy (load || barrier || compute || store) — VMEM idle during compute,
// 2.4 TB/s vs fillBuffer's 6.5 TB/s on the same chip. Also 128 scalar b32
// LDS ops/thread from misaligned ROW=33.
//
// R3: single-wave blocks (TPB=64). __syncthreads is elided by the backend
// (block == one wave), so every wave runs its load->transpose->compute->
// store pipeline independently; ~16 resident wave-blocks/CU (LDS 9216 B)
// give ~128 KB of loads in flight per CU — VMEM streams continuously.
// ROW=36 keeps rows 16B-aligned: all LDS traffic is b128, and every access
// pattern lands at 2 lanes/bank-quad per 16-lane phase (= free, m136).
//
// Numerics: bit-exact f32 replication of the numpy reference (contract off,
// left-assoc order, literal spike-blend). LDS round-trip preserves bits.

#define T_STEPS 32
#define TPB 64          // one wave per block: no barriers, no convoy
#define ROW 36          // floats; 144 B rows, 16B-aligned, 9 bank-quads

__global__ __launch_bounds__(TPB) void izhikevich_kernel(
    const float* __restrict__ x,
    const float* __restrict__ pa,
    const float* __restrict__ pb,
    const float* __restrict__ pc,
    const float* __restrict__ pd,
    float* __restrict__ out)
{
#pragma clang fp contract(off)
    __shared__ float lds[TPB * ROW];            // 9216 B

    const int t = threadIdx.x;
    const size_t base = (size_t)blockIdx.x * (TPB * T_STEPS);

    const float a = pa[0];
    const float b = pb[0];
    const float c = pc[0];
    const float d = pd[0];

    // ---- Phase 1: coalesced global loads (8 KB/wave in flight) -----------
    const float4* __restrict__ xin = reinterpret_cast<const float4*>(x + base);
    float4 ch[8];
#pragma unroll
    for (int k = 0; k < 8; ++k) ch[k] = xin[k * TPB + t];

    // ---- Phase 2: transposing scatter into LDS (b128, 2-way = free) ------
    // float4 #(k*64+t) holds neuron ng = k*8 + t/8, times (t%8)*4 .. +3.
#pragma unroll
    for (int k = 0; k < 8; ++k) {
        const int ng = k * 8 + (t >> 3);
        const int tg = (t & 7) * 4;
        *reinterpret_cast<float4*>(&lds[ng * ROW + tg]) = ch[k];
    }
    __syncthreads();    // single-wave block: compiles to waitcnt only

    // ---- Phase 3: own-row gather (b128) ----------------------------------
    float xs[T_STEPS];
#pragma unroll
    for (int j = 0; j < 8; ++j)
        *reinterpret_cast<float4*>(&xs[j * 4]) =
            *reinterpret_cast<const float4*>(&lds[t * ROW + j * 4]);

    // ---- Phase 4: recurrence (bit-exact), spikes back to own row ---------
    float v = 0.0f;
    float u = 0.0f;
#pragma unroll
    for (int j = 0; j < 8; ++j) {
        float4 sp;
        float* sf = reinterpret_cast<float*>(&sp);
#pragma unroll
        for (int i = 0; i < 4; ++i) {
            const float xt = xs[j * 4 + i];
            // dv = 0.04*v*v + 5.0*v + 140.0 - u + x_t   (left-assoc, no fma)
            const float t1 = (0.04f * v) * v;
            const float t2 = 5.0f * v;
            const float dv = (((t1 + t2) + 140.0f) - u) + xt;
            v = v + dv;                          // DT = 1.0 exact
            const float du = a * ((b * v) - u);
            u = u + du;
            const float spike = (v >= 30.0f) ? 1.0f : 0.0f;
            const float oms = 1.0f - spike;
            v = (v * oms) + (c * spike);         // exact for spike in {0,1}
            u = u + (d * spike);
            sf[i] = spike;
        }
        *reinterpret_cast<float4*>(&lds[t * ROW + j * 4]) = sp;
    }
    __syncthreads();    // waitcnt only

    // ---- Phase 5: inverse transpose gather + coalesced stores ------------
    float4* __restrict__ op = reinterpret_cast<float4*>(out + base);
#pragma unroll
    for (int k = 0; k < 8; ++k) {
        const int ng = k * 8 + (t >> 3);
        const int tg = (t & 7) * 4;
        const float4 o = *reinterpret_cast<const float4*>(&lds[ng * ROW + tg]);
        op[k * TPB + t] = o;
    }
}

extern "C" void kernel_launch(void* const* d_in, const int* in_sizes, int n_in,
                              void* d_out, int out_size, void* d_ws, size_t ws_size,
                              hipStream_t stream) {
    const float* x  = (const float*)d_in[0];
    const float* pa = (const float*)d_in[1];
    const float* pb = (const float*)d_in[2];
    const float* pc = (const float*)d_in[3];
    const float* pd = (const float*)d_in[4];
    float* out = (float*)d_out;

    const int n_neurons = in_sizes[0] / T_STEPS;   // 1,048,576
    const int grid = n_neurons / TPB;              // 16384 (exact)

    izhikevich_kernel<<<grid, TPB, 0, stream>>>(x, pa, pb, pc, pd, out);
}